// Round 16
// baseline (377.781 us; speedup 1.0000x reference)
//
#include <hip/hip_runtime.h>
#include <hip/hip_bf16.h>

#define TS 20
#define NWORDS 16384
#define NBLK 256                    // 1 block/CU; bid>>7 = dir

typedef __attribute__((ext_vector_type(8))) short s8v;
typedef __attribute__((ext_vector_type(16))) float f16v;

#define L2E 1.4426950408889634f

__device__ __forceinline__ unsigned short bf16_rne(float f) {
  union { float f; unsigned u; } x; x.f = f;
  unsigned r = x.u + 0x7fffu + ((x.u >> 16) & 1u);
  return (unsigned short)(r >> 16);
}

// tab2[dir][c][u] = (-L2E*(xz + b_rec_z), -L2E*(xr + b_rec_r)); xg incl b_in.
// tabh[dir][c][u] = 2*L2E*xh.   (b_rec_h cannot fold: it sits inside r*(...))
__global__ void build_tab(const float* __restrict__ emb,
                          const float* __restrict__ wkF, const float* __restrict__ bF,
                          const float* __restrict__ wkB, const float* __restrict__ bB,
                          float* __restrict__ tab2, float* __restrict__ tabh) {
  int gid = blockIdx.x * 256 + threadIdx.x;
  if (gid >= 2 * 129 * 768) return;
  int dir = gid / (129 * 768);
  int rem = gid - dir * (129 * 768);
  int c = rem / 768, j = rem - (rem / 768) * 768;
  int g = j >> 8, u = j & 255;
  const float* Wk = dir ? wkB : wkF;
  const float* bb = dir ? bB : bF;
  float s = bb[j];                       // b[0] row = input bias
  const float* er = emb + c * 128;
  #pragma unroll 4
  for (int d = 0; d < 128; ++d) s = fmaf(er[d], Wk[d * 768 + j], s);
  if (g < 2) tab2[(((size_t)dir * 129 + c) * 256 + u) * 2 + g] = -L2E * (s + bb[768 + j]);
  else       tabh[((size_t)dir * 129 + c) * 256 + u] = 2.f * L2E * s;
}

// Pack Wr into bf16 32x32x16-MFMA B-fragment order, pre-scaled per gate.
// wp[dir][g*8+ct][k][lane] = 8 bf16: Wr[k*16 + (lane>>5)*8 + e][g*256 + ct*32 + (lane&31)]
// A/B use the SAME assumed k-map -> dot product exact for any HW slot
// assignment (r1-verified permutation-invariance argument).
__global__ void pack_wr32(const float* __restrict__ wrF, const float* __restrict__ wrB,
                          uint4* __restrict__ wp) {
  int gid = blockIdx.x * 256 + threadIdx.x;
  if (gid >= 2 * 24 * 16 * 64) return;
  int dir = gid / (24 * 16 * 64);
  int rem = gid - dir * (24 * 16 * 64);
  int gct = rem / (16 * 64);
  int k = (rem / 64) & 15;
  int lane = rem & 63;
  int g = gct >> 3, ct = gct & 7;
  const float* Wr = dir ? wrB : wrF;
  const int n = g * 256 + ct * 32 + (lane & 31);
  const int k0 = k * 16 + (lane >> 5) * 8;
  const float sc = (g == 2) ? (2.f * L2E) : (-L2E);
  union { unsigned short v[8]; uint4 q; } u;
  #pragma unroll
  for (int e = 0; e < 8; ++e) u.v[e] = bf16_rne(sc * Wr[(k0 + e) * 768 + n]);
  wp[gid] = u.q;
}

// 256 blocks (1/CU) x 512 threads (8 waves). 32x32x16 MFMA geometry:
// wave = 32 units x ALL 3 gates, 32 words/step (4 groups of 32).
// z,r weights in 128 regs (AGPR-parked, B-operand safe — r8/r13 evidence);
// h-gate panel (128KB) in LDS, streamed ONCE per 32 words (was once per 16).
// C/D layout (HW-verified m74/m101): col=lane&31, row=(i&3)+8*(i>>2)+4*(lane>>5).
// Single-buffer h state: [MFMA reads rows 0-31] b1 [epi writes rows 0-31] b2.
__global__ __launch_bounds__(512, 2) void gru_main(
    const int* __restrict__ chars, const float* __restrict__ tab2,
    const float* __restrict__ tabh, const uint4* __restrict__ wrp,
    const float* __restrict__ bf_, const float* __restrict__ bb_,
    float* __restrict__ out) {
  const int bid = blockIdx.x;
  const int dir = bid >> 7;            // 128 blocks per direction
  const int wslot = bid & 127;
  const float2* T2 = (const float2*)tab2 + (size_t)dir * 129 * 256;
  const float*  TH = tabh + (size_t)dir * 129 * 256;
  const uint4* WP = wrp + dir * (24 * 16 * 64);
  const float* brec = (dir ? bb_ : bf_) + 768;   // b[1] = recurrent bias

  const int tid = threadIdx.x;
  const int w = tid >> 6, lane = tid & 63;
  const int lo = lane & 31, hi = lane >> 5;
  const int u = w * 32 + lo;           // this lane's single output column

  __shared__ uint4 bhl[8192];                    // 128KB h-gate weights (g=2)
  __shared__ unsigned short hbf[32][260];        // 16.25KB; 520B stride -> balanced banks
  __shared__ int sch[32 * TS];                   // 2.56KB chars

  for (int i = tid; i < 8192; i += 512) bhl[i] = WP[16384 + i];   // gct=16..23

  // z,r weights resident: 2 gates x 16 k = 32 uint4 = 128 regs.
  uint4 Wz[16], Wrr[16];
  #pragma unroll
  for (int k = 0; k < 16; ++k) {
    Wz[k]  = WP[((0 + w) * 16 + k) * 64 + lane];     // gct = w
    Wrr[k] = WP[((8 + w) * 16 + k) * 64 + lane];     // gct = 8 + w
  }

  const float brh = 2.f * L2E * brec[512 + u];

  #pragma unroll 1
  for (int grp = 0; grp < 4; ++grp) {
    const int word0 = wslot * 128 + grp * 32;

    for (int i = tid; i < 32 * 260 / 2; i += 512) ((unsigned*)&hbf[0][0])[i] = 0;
    for (int i = tid; i < 32 * TS; i += 512) sch[i] = chars[word0 * TS + i];

    float h[16];
    #pragma unroll
    for (int i = 0; i < 16; ++i) h[i] = 0.f;

    __syncthreads();

    #pragma unroll 1
    for (int t = 0; t < TS; ++t) {
      const int ts = dir ? (TS - 1 - t) : t;

      f16v az, ar, ah;
      #pragma unroll
      for (int i = 0; i < 16; ++i) { az[i] = 0.f; ar[i] = 0.f; ah[i] = brh; }

      #pragma unroll
      for (int k = 0; k < 16; ++k) {
        const s8v aa = __builtin_bit_cast(s8v, *(const uint4*)&hbf[lo][k * 16 + hi * 8]);
        az = __builtin_amdgcn_mfma_f32_32x32x16_bf16(aa, __builtin_bit_cast(s8v, Wz[k]),  az, 0, 0, 0);
        ar = __builtin_amdgcn_mfma_f32_32x32x16_bf16(aa, __builtin_bit_cast(s8v, Wrr[k]), ar, 0, 0, 0);
        ah = __builtin_amdgcn_mfma_f32_32x32x16_bf16(aa, __builtin_bit_cast(s8v, bhl[(w * 16 + k) * 64 + lane]), ah, 0, 0, 0);
      }
      __syncthreads();   // b1: all h-row reads complete

      // epilogue: all gathers in-epilogue (nothing live across MFMA phase);
      // half-wave shares the word-row -> T2/TH reads are 256B contiguous.
      #pragma unroll
      for (int i = 0; i < 16; ++i) {
        const int row = (i & 3) + ((i >> 2) << 3) + (hi << 2);   // C/D row
        const int c = sch[row * TS + ts];
        const int off = c * 256 + u;
        const float2 p = T2[off];
        const float  q = TH[off];
        const float z  = __builtin_amdgcn_rcpf(1.f + __builtin_amdgcn_exp2f(p.x + az[i]));
        const float rr = __builtin_amdgcn_rcpf(1.f + __builtin_amdgcn_exp2f(p.y + ar[i]));
        const float hc = fmaf(-2.f, __builtin_amdgcn_rcpf(
            1.f + __builtin_amdgcn_exp2f(fmaf(rr, ah[i], q))), 1.f);
        const float hp = h[i];
        float hn = fmaf(1.f - z, hc - hp, hp);
        hn = (c != 0) ? hn : hp;
        h[i] = hn;
        hbf[row][u] = bf16_rne(hn);
      }
      __syncthreads();   // b2: writes complete before next step's reads
    }

    // store this group's outputs (half-wave-contiguous rows)
    #pragma unroll
    for (int i = 0; i < 16; ++i) {
      const int row = (i & 3) + ((i >> 2) << 3) + (hi << 2);
      out[(size_t)(word0 + row) * 512 + dir * 256 + u] = h[i];
    }
    __syncthreads();   // guard hbf/sch reuse vs next group's init
  }
}

extern "C" void kernel_launch(void* const* d_in, const int* in_sizes, int n_in,
                              void* d_out, int out_size, void* d_ws, size_t ws_size,
                              hipStream_t stream) {
  const int* chars = (const int*)d_in[0];
  const float* emb = (const float*)d_in[1];
  const float* wkF = (const float*)d_in[2];
  const float* wrF = (const float*)d_in[3];
  const float* bF  = (const float*)d_in[4];
  const float* wkB = (const float*)d_in[5];
  const float* wrB = (const float*)d_in[6];
  const float* bB  = (const float*)d_in[7];
  float* outp = (float*)d_out;

  float* tab2 = (float*)d_ws;                                   // 2*129*256*8B  = 528384
  float* tabh = (float*)((char*)d_ws + 528384);                 // 2*129*256*4B  = 264192
  uint4* wrp  = (uint4*)((char*)d_ws + 528384 + 264192);        // 2*24*16*64*16B = 786432

  build_tab<<<(2 * 129 * 768 + 255) / 256, 256, 0, stream>>>(emb, wkF, bF, wkB, bB, tab2, tabh);
  pack_wr32<<<(2 * 24 * 16 * 64 + 255) / 256, 256, 0, stream>>>(wrF, wrB, wrp);
  gru_main<<<NBLK, 512, 0, stream>>>(chars, tab2, tabh, wrp, bF, bB, outp);
}

// Round 17
// 289.510 us; speedup vs baseline: 1.3049x; 1.3049x over previous
//
#include <hip/hip_runtime.h>
#include <hip/hip_bf16.h>

#define TS 20
#define DNUM 128
#define NWORDS 16384
#define NBLK 256                    // 1 block/CU; bid>>7 = dir

typedef __attribute__((ext_vector_type(8))) short s8v;
typedef __attribute__((ext_vector_type(4))) float f4v;

#define L2E 1.4426950408889634f

__device__ __forceinline__ unsigned short bf16_rne(float f) {
  union { float f; unsigned u; } x; x.f = f;
  unsigned r = x.u + 0x7fffu + ((x.u >> 16) & 1u);
  return (unsigned short)(r >> 16);
}

// tab2[dir][c][u] = (-L2E*(xz + b_rec_z), -L2E*(xr + b_rec_r)); xg incl b_in.
// tabh[dir][c][u] = 2*L2E*xh.   (b_rec_h cannot fold: it sits inside r*(...))
__global__ void build_tab(const float* __restrict__ emb,
                          const float* __restrict__ wkF, const float* __restrict__ bF,
                          const float* __restrict__ wkB, const float* __restrict__ bB,
                          float* __restrict__ tab2, float* __restrict__ tabh) {
  int gid = blockIdx.x * 256 + threadIdx.x;
  if (gid >= 2 * 129 * 768) return;
  int dir = gid / (129 * 768);
  int rem = gid - dir * (129 * 768);
  int c = rem / 768, j = rem - (rem / 768) * 768;
  int g = j >> 8, u = j & 255;
  const float* Wk = dir ? wkB : wkF;
  const float* bb = dir ? bB : bF;
  float s = bb[j];                       // b[0] row = input bias
  const float* er = emb + c * DNUM;
  #pragma unroll 4
  for (int d = 0; d < DNUM; ++d) s = fmaf(er[d], Wk[d * 768 + j], s);
  if (g < 2) tab2[(((size_t)dir * 129 + c) * 256 + u) * 2 + g] = -L2E * (s + bb[768 + j]);
  else       tabh[((size_t)dir * 129 + c) * 256 + u] = 2.f * L2E * s;
}

// Pack Wr into bf16 MFMA-B-fragment order (verified r1), pre-scaled per gate.
__global__ void pack_wr(const float* __restrict__ wrF, const float* __restrict__ wrB,
                        uint4* __restrict__ wp) {
  int gid = blockIdx.x * 256 + threadIdx.x;
  if (gid >= 2 * 48 * 8 * 64) return;
  int dir = gid / (48 * 8 * 64);
  int rem = gid - dir * (48 * 8 * 64);
  int ct = rem / (8 * 64);
  int kk = (rem / 64) & 7;
  int lane = rem & 63;
  const float* Wr = dir ? wrB : wrF;
  int n = ct * 16 + (lane & 15);
  int k0 = kk * 32 + (lane >> 4) * 8;
  const float sc = (ct >> 4) == 2 ? (2.f * L2E) : (-L2E);
  union { unsigned short v[8]; uint4 q; } u;
  #pragma unroll
  for (int e = 0; e < 8; ++e) u.v[e] = bf16_rne(sc * Wr[(k0 + e) * 768 + n]);
  wp[gid] = u.q;
}

// r13/r15 champion (byte-identical): dbuf h state, 1 barrier/step.
// 256 blocks (1/CU) x 512 threads (8 waves, 2/SIMD). Wave = 32 units x 3
// gates, 16 words/step. z,r weights in 128 regs (AGPR-parked by compiler —
// B-operands tolerate this, r8 evidence); h-gate panel in 128KB LDS.
__global__ __launch_bounds__(512, 2) void gru_main(
    const int* __restrict__ chars, const float* __restrict__ tab2,
    const float* __restrict__ tabh, const uint4* __restrict__ wrp,
    const float* __restrict__ bf_, const float* __restrict__ bb_,
    float* __restrict__ out) {
  const int bid = blockIdx.x;
  const int dir = bid >> 7;            // 128 blocks per direction
  const int wslot = bid & 127;
  const float2* T2 = (const float2*)tab2 + (size_t)dir * 129 * 256;
  const float*  TH = tabh + (size_t)dir * 129 * 256;
  const uint4* WP = wrp + dir * (48 * 8 * 64);
  const float* brec = (dir ? bb_ : bf_) + 768;   // b[1] = recurrent bias

  const int tid = threadIdx.x;
  const int w = tid >> 6, lane = tid & 63;
  const int lr = lane >> 4, lc = lane & 15;
  const int u0 = w * 32 + lc, u1 = u0 + 16;      // wave's two unit-tiles

  __shared__ uint4 bhl[8192];                    // 128KB h-gate weights
  __shared__ unsigned short hbf[2][16][264];     // 16.5KB dbuf; 528B stride -> 2-way
  __shared__ int sch[16 * TS];                   // 1.28KB chars

  for (int i = tid; i < 8192; i += 512) bhl[i] = WP[16384 + i];

  // z,r weights resident: 2 ct x 8 kk x 2 gates = 32 uint4 = 128 regs.
  uint4 Wz[2][8], Wrr[2][8];
  #pragma unroll
  for (int ct = 0; ct < 2; ++ct)
    #pragma unroll
    for (int kk = 0; kk < 8; ++kk) {
      Wz[ct][kk]  = WP[((w * 2 + ct) * 8 + kk) * 64 + lane];
      Wrr[ct][kk] = WP[((16 + w * 2 + ct) * 8 + kk) * 64 + lane];
    }

  float brh[2];
  brh[0] = 2.f * L2E * brec[512 + u0];
  brh[1] = 2.f * L2E * brec[512 + u1];

  #pragma unroll 1
  for (int grp = 0; grp < 8; ++grp) {
    const int word0 = wslot * 128 + grp * 16;

    for (int i = tid; i < 16 * 264 / 2; i += 512)
      ((unsigned*)&hbf[0][0][0])[i] = 0;         // zero buf 0 only
    for (int i = tid; i < 16 * TS; i += 512) sch[i] = chars[word0 * TS + i];

    float h[2][4];
    #pragma unroll
    for (int ct = 0; ct < 2; ++ct)
      #pragma unroll
      for (int r = 0; r < 4; ++r) h[ct][r] = 0.f;

    __syncthreads();

    #pragma unroll 1
    for (int t = 0; t < TS; ++t) {
      const int ts = dir ? (TS - 1 - t) : t;
      const unsigned short (*rd)[264] = hbf[t & 1];
      unsigned short (*wr)[264] = hbf[(t + 1) & 1];

      // cc + z,r-logit prefetch (L2 latency hides under the MFMA phase)
      int cc[4];
      #pragma unroll
      for (int r = 0; r < 4; ++r) cc[r] = sch[(lr * 4 + r) * TS + ts];
      float2 p[2][4];
      #pragma unroll
      for (int ct = 0; ct < 2; ++ct)
        #pragma unroll
        for (int r = 0; r < 4; ++r)
          p[ct][r] = T2[cc[r] * 256 + (ct ? u1 : u0)];

      f4v az[2], ar[2], ah[2];
      #pragma unroll
      for (int ct = 0; ct < 2; ++ct) {
        az[ct] = f4v{0.f, 0.f, 0.f, 0.f};
        ar[ct] = az[ct];
        ah[ct] = f4v{brh[ct], brh[ct], brh[ct], brh[ct]};
      }
      #pragma unroll
      for (int kk = 0; kk < 8; ++kk) {
        const s8v aa = __builtin_bit_cast(s8v, *(const uint4*)&rd[lc][kk * 32 + lr * 8]);
        #pragma unroll
        for (int ct = 0; ct < 2; ++ct) {
          const uint4 bh = bhl[((w * 2 + ct) * 8 + kk) * 64 + lane];
          az[ct] = __builtin_amdgcn_mfma_f32_16x16x32_bf16(aa, __builtin_bit_cast(s8v, Wz[ct][kk]),  az[ct], 0, 0, 0);
          ar[ct] = __builtin_amdgcn_mfma_f32_16x16x32_bf16(aa, __builtin_bit_cast(s8v, Wrr[ct][kk]), ar[ct], 0, 0, 0);
          ah[ct] = __builtin_amdgcn_mfma_f32_16x16x32_bf16(aa, __builtin_bit_cast(s8v, bh),          ah[ct], 0, 0, 0);
        }
      }

      // epilogue: no barrier needed before it — MFMA reads rd, epi writes wr
      #pragma unroll
      for (int ct = 0; ct < 2; ++ct)
        #pragma unroll
        for (int r = 0; r < 4; ++r) {
          const float q = TH[cc[r] * 256 + (ct ? u1 : u0)];
          const float z  = __builtin_amdgcn_rcpf(1.f + __builtin_amdgcn_exp2f(p[ct][r].x + az[ct][r]));
          const float rr = __builtin_amdgcn_rcpf(1.f + __builtin_amdgcn_exp2f(p[ct][r].y + ar[ct][r]));
          const float hc = fmaf(-2.f, __builtin_amdgcn_rcpf(
              1.f + __builtin_amdgcn_exp2f(fmaf(rr, ah[ct][r], q))), 1.f);
          const float hp = h[ct][r];
          float hn = fmaf(1.f - z, hc - hp, hp);
          hn = (cc[r] != 0) ? hn : hp;
          h[ct][r] = hn;
          wr[lr * 4 + r][ct ? u1 : u0] = bf16_rne(hn);
        }
      __syncthreads();   // single barrier: wr complete before next step reads
    }

    // store this group's outputs
    #pragma unroll
    for (int ct = 0; ct < 2; ++ct)
      #pragma unroll
      for (int r = 0; r < 4; ++r)
        out[(size_t)(word0 + lr * 4 + r) * 512 + dir * 256 + (ct ? u1 : u0)] = h[ct][r];
    __syncthreads();   // guard hbf/sch reuse vs next group's init
  }
}

extern "C" void kernel_launch(void* const* d_in, const int* in_sizes, int n_in,
                              void* d_out, int out_size, void* d_ws, size_t ws_size,
                              hipStream_t stream) {
  const int* chars = (const int*)d_in[0];
  const float* emb = (const float*)d_in[1];
  const float* wkF = (const float*)d_in[2];
  const float* wrF = (const float*)d_in[3];
  const float* bF  = (const float*)d_in[4];
  const float* wkB = (const float*)d_in[5];
  const float* wrB = (const float*)d_in[6];
  const float* bB  = (const float*)d_in[7];
  float* outp = (float*)d_out;

  float* tab2 = (float*)d_ws;                                   // 2*129*256*8B  = 528384
  float* tabh = (float*)((char*)d_ws + 528384);                 // 2*129*256*4B  = 264192
  uint4* wrp  = (uint4*)((char*)d_ws + 528384 + 264192);        // 2*48*8*64*16B = 786432

  build_tab<<<(2 * 129 * 768 + 255) / 256, 256, 0, stream>>>(emb, wkF, bF, wkB, bB, tab2, tabh);
  pack_wr<<<(2 * 48 * 8 * 64 + 255) / 256, 256, 0, stream>>>(wrF, wrB, wrp);
  gru_main<<<NBLK, 512, 0, stream>>>(chars, tab2, tabh, wrp, bF, bB, outp);
}